// Round 6
// baseline (32.770 us; speedup 1.0000x reference)
//
#include <hip/hip_runtime.h>

typedef unsigned long long u64;
typedef unsigned int u32;

#define HW 65536            // 256*256 attention positions per batch
#define NB 8                // batch
#define NSEL 16             // top-k
#define NC 3
#define HH 2048             // x_high H=W

// surrogate key: order(log a - log(-log u)) == order(a / (-log2 u)).
__device__ __forceinline__ u32 wkey(float a, float u) {
  float v = __builtin_amdgcn_logf(u);            // log2(u) < 0
  float w = a * __builtin_amdgcn_rcpf(-v);       // a / (-log2 u) > 0
  return __float_as_uint(w);                     // positive floats order as uints
}

__device__ __forceinline__ u64 wave_max64(u64 k) {
#pragma unroll
  for (int off = 1; off < 64; off <<= 1) {
    u32 lo = __shfl_xor((u32)k, off, 64);
    u32 hi = __shfl_xor((u32)(k >> 32), off, 64);
    u64 o = ((u64)hi << 32) | lo;
    if (o > k) k = o;
  }
  return k;
}

#define CMPSWAP(a, b) { if ((b) > (a)) { u64 t_ = (a); (a) = (b); (b) = t_; } }

// Kernel 1: 512 blocks x 256 thr. Block-local top-16 of its 1024 elements
// (float4 loads; lane owns 4 contiguous elems), sorted 16-list -> cand.
__global__ __launch_bounds__(256) void scan_topk(
    const float* __restrict__ att, const float* __restrict__ noise,
    u64* __restrict__ cand) {
  const int tid = threadIdx.x;
  const int lane = tid & 63;
  const int wave = tid >> 6;
  const int b = blockIdx.x >> 6;       // batch
  const int blk = blockIdx.x & 63;     // block within batch (1024 elems)

  __shared__ u64 s_wtop[64];           // 4 waves x 16

  const int ebase = blk * 1024 + wave * 256;     // within-batch element base
  const float4 av = *reinterpret_cast<const float4*>(att + b * HW + ebase + (lane << 2));
  const float4 uv = *reinterpret_cast<const float4*>(noise + b * HW + ebase + (lane << 2));

  u64 k4[4];
  {
    const u32 e0 = (u32)(ebase + (lane << 2));
    k4[0] = ((u64)wkey(av.x, uv.x) << 32) | (0xFFFFFFFFu - e0);
    k4[1] = ((u64)wkey(av.y, uv.y) << 32) | (0xFFFFFFFFu - (e0 + 1));
    k4[2] = ((u64)wkey(av.z, uv.z) << 32) | (0xFFFFFFFFu - (e0 + 2));
    k4[3] = ((u64)wkey(av.w, uv.w) << 32) | (0xFFFFFFFFu - (e0 + 3));
  }
  // descending sort-4 network
  CMPSWAP(k4[0], k4[1]); CMPSWAP(k4[2], k4[3]);
  CMPSWAP(k4[0], k4[2]); CMPSWAP(k4[1], k4[3]);
  CMPSWAP(k4[1], k4[2]);

  // per-wave top-16 -> LDS (16 extraction rounds; keys globally distinct)
#pragma unroll
  for (int r = 0; r < NSEL; r++) {
    u64 g = wave_max64(k4[0]);
    if (k4[0] == g) {                  // exactly one winning lane
      s_wtop[wave * 16 + r] = g;
      k4[0] = k4[1]; k4[1] = k4[2]; k4[2] = k4[3]; k4[3] = 0ULL;
    }
  }
  __syncthreads();

  // wave 0: merge 64 -> sorted block top-16 -> cand
  if (wave == 0) {
    u64 kk = s_wtop[lane];
#pragma unroll
    for (int r = 0; r < NSEL; r++) {
      u64 g = wave_max64(kk);
      if (kk == g) {
        cand[(size_t)blockIdx.x * NSEL + r] = g;   // sorted position r
        kk = 0ULL;
      }
    }
  }
}

// Kernel 2: 8 blocks x 64. Merge the batch's 64 sorted 16-lists once.
// Writes idx_sel (for the patch kernel) + att_out (bit-exact gather).
__global__ __launch_bounds__(64) void final_merge(
    const u64* __restrict__ cand, const float* __restrict__ att,
    int* __restrict__ idx_sel, float* __restrict__ att_out) {
  const int b = blockIdx.x;
  const int lane = threadIdx.x;

  const u64* cb = cand + (size_t)(b * 64 + lane) * NSEL;  // lane = source block
  u64 lst[NSEL];
#pragma unroll
  for (int j = 0; j < NSEL; j++) lst[j] = cb[j];          // sorted descending
  u64 won = 0ULL;
#pragma unroll
  for (int r = 0; r < NSEL; r++) {
    u64 g = wave_max64(lst[0]);
    if (lane == r) won = g;
    if (lst[0] == g) {                 // unique winner (distinct keys)
#pragma unroll
      for (int i = 0; i < NSEL - 1; i++) lst[i] = lst[i + 1];
      lst[NSEL - 1] = 0ULL;
    }
  }
  if (lane < NSEL) {
    u32 e = 0xFFFFFFFFu - (u32)(won & 0xFFFFFFFFu);
    idx_sel[b * NSEL + lane] = (int)e;
    att_out[b * NSEL + lane] = att[b * HW + (int)e];      // bit-exact gather
  }
}

// Kernel 3: 1536 blocks x 256. Quarter-patch (32 rows) float4 copy.
// Block-uniform idx load -> s_load, no LDS, no barriers.
__global__ __launch_bounds__(256) void patch_extract(
    const float* __restrict__ xh, const int* __restrict__ idx_sel,
    float* __restrict__ out) {
  const int q4 = blockIdx.x & 3;        // quarter (32 rows)
  const int pairc = blockIdx.x >> 2;    // (b*16+n)*3 + c
  const int c = pairc % 3;
  const int bn = pairc / 3;             // b*16 + n
  const int b = bn >> 4;
  const int tid = threadIdx.x;

  const int e = idx_sel[bn];            // uniform -> scalar load
  const int r0 = (e >> 8) * 8 - 60 + q4 * 32;   // unpadded row start
  const int c0 = (e & 255) * 8 - 60;            // unpadded col start (mult of 4)
  const float* src = xh + ((size_t)(b * NC + c) << 22);
  float4* dst = (float4*)out + (size_t)pairc * 4096 + (size_t)q4 * 1024;

#pragma unroll
  for (int it = 0; it < 4; it++) {
    const int i = it * 256 + tid;       // [0,1024) float4 within quarter
    const int pr = i >> 5;              // row within quarter 0..31
    const int q = i & 31;               // float4 index within row
    const int r = r0 + pr;
    const int cc = c0 + (q << 2);
    float4 v = make_float4(0.f, 0.f, 0.f, 0.f);
    // cc multiple of 4 -> float4 fully in-bounds or fully out
    if ((u32)r < (u32)HH && (u32)cc < (u32)HH) {
      v = *reinterpret_cast<const float4*>(src + ((size_t)r << 11) + cc);
    }
    dst[i] = v;
  }
}

extern "C" void kernel_launch(void* const* d_in, const int* in_sizes, int n_in,
                              void* d_out, int out_size, void* d_ws, size_t ws_size,
                              hipStream_t stream) {
  (void)in_sizes; (void)n_in; (void)out_size; (void)ws_size;
  // inputs: 0=x_low (unused, shape-only), 1=x_high, 2=attention, 3=noise_u
  const float* x_high = (const float*)d_in[1];
  const float* att    = (const float*)d_in[2];
  const float* noise  = (const float*)d_in[3];
  float* out = (float*)d_out;
  float* att_out = out + (size_t)NB * NSEL * NC * 128 * 128;   // 6291456

  char* ws = (char*)d_ws;
  u64* cand    = (u64*)ws;                       // 512 * 16 u64 = 64 KiB
  int* idx_sel = (int*)(ws + 512 * NSEL * 8);    // 128 ints

  scan_topk<<<dim3(NB * 64), dim3(256), 0, stream>>>(att, noise, cand);
  final_merge<<<dim3(NB), dim3(64), 0, stream>>>(cand, att, idx_sel, att_out);
  patch_extract<<<dim3(NB * NSEL * NC * 4), dim3(256), 0, stream>>>(
      x_high, idx_sel, out);
}